// Round 11
// baseline (292.851 us; speedup 1.0000x reference)
//
#include <hip/hip_runtime.h>
#include <math.h>

#if __has_builtin(__builtin_amdgcn_cvt_pk_f32_fp8) && __has_builtin(__builtin_amdgcn_cvt_pk_fp8_f32)
#define HAS_FP8 1
#else
#define HAS_FP8 0
#endif

// Problem constants
constexpr int CB = 4, CS = 512, CD = 768, CFF = 3072, CH = 12, CHD = 64;
constexpr int CT = CB * CS;            // 2048 tokens
constexpr int PH = 4, KD = 512, NK = 128, KNN = 32, HALF = 256;

typedef __attribute__((ext_vector_type(8))) short short8_t;   // 8 bf16 (4 VGPRs)
typedef __attribute__((ext_vector_type(4))) float f32x4;      // MFMA accumulator
typedef __attribute__((ext_vector_type(2))) float f32x2;

__device__ __forceinline__ unsigned short f2bf(float f) {
    unsigned int u = __float_as_uint(f);
    return (unsigned short)((u + 0x7FFF + ((u >> 16) & 1)) >> 16);  // RNE
}
__device__ __forceinline__ float bf2f(unsigned short h) {
    return __uint_as_float(((unsigned)h) << 16);
}

// async global->LDS, 16B per lane; LDS dest = wave-uniform base + lane*16
__device__ __forceinline__ void ld_lds16(const unsigned short* g, unsigned short* l) {
    __builtin_amdgcn_global_load_lds(
        (const __attribute__((address_space(1))) void*)g,
        (__attribute__((address_space(3))) void*)l, 16, 0, 0);
}

// ------------------------------------------------------------ fp32->bf16 --
__global__ __launch_bounds__(256) void cvt_bf16x4(const float* __restrict__ in,
    unsigned short* __restrict__ out, int n4)
{
    for (int i = blockIdx.x * 256 + threadIdx.x; i < n4; i += gridDim.x * 256) {
        float4 v = ((const float4*)in)[i];
        ushort4 o = { f2bf(v.x), f2bf(v.y), f2bf(v.z), f2bf(v.w) };
        ((ushort4*)out)[i] = o;
    }
}

#if HAS_FP8
// ------------------------------------------------------------ fp32->fp8 ---
__global__ __launch_bounds__(256) void cvt_fp8x4(const float* __restrict__ in,
    unsigned* __restrict__ out, int n4)
{
    for (int i = blockIdx.x * 256 + threadIdx.x; i < n4; i += gridDim.x * 256) {
        float4 v = ((const float4*)in)[i];
        int p = 0;
        p = __builtin_amdgcn_cvt_pk_fp8_f32(v.x, v.y, p, false);
        p = __builtin_amdgcn_cvt_pk_fp8_f32(v.z, v.w, p, true);
        out[i] = (unsigned)p;
    }
}
#endif

// ------------------------- fused prep: weight transposes + x/keys cvt -----
__global__ __launch_bounds__(256) void prep_kernel(
    const float* __restrict__ Wq, const float* __restrict__ Wk,
    const float* __restrict__ Wv, const float* __restrict__ Wo,
    const float* __restrict__ Wi, const float* __restrict__ Wd,
    const float* __restrict__ Wpq, unsigned short* __restrict__ wt,
    const float* __restrict__ x, unsigned short* __restrict__ xb,
    const float* __restrict__ keys, unsigned short* __restrict__ keysb)
{
    const int b = blockIdx.x, tid = threadIdx.x;
    if (b < 6528) {
        __shared__ unsigned short ts[32][72];   // [n][k], 16B-aligned rows
        const float* W; unsigned short* WT; int K, N, tile;
        if (b < 1152) {
            int z = b / 288; tile = b - z * 288;
            W = (z == 0) ? Wq : (z == 1) ? Wk : (z == 2) ? Wv : Wo;
            WT = wt + (size_t)z * 589824; K = 768; N = 768;
        } else if (b < 2304) {
            tile = b - 1152; W = Wi; WT = wt + 4 * 589824; K = 768; N = 3072;
        } else if (b < 3456) {
            tile = b - 2304; W = Wd; WT = wt + 4 * 589824 + 2359296; K = 3072; N = 768;
        } else {
            tile = b - 3456; W = Wpq; WT = wt + 4 * 589824 + 2 * 2359296; K = 3072; N = 2048;
        }
        const int nx = N >> 5;
        const int n0 = (tile % nx) * 32, k0 = (tile / nx) * 64;
        const int c = tid & 31, rr = tid >> 5;
#pragma unroll
        for (int i = 0; i < 8; i++) {
            int r = rr + i * 8;
            ts[c][r] = f2bf(W[(size_t)(k0 + r) * N + n0 + c]);
        }
        __syncthreads();
        const int nn = tid >> 3, kc = tid & 7;
        uint4 v = *(const uint4*)&ts[nn][kc * 8];
        *(uint4*)&WT[(size_t)(n0 + nn) * K + k0 + kc * 8] = v;
    } else if (b < 8064) {
        const int i = (b - 6528) * 256 + tid;
        float4 v = ((const float4*)x)[i];
        ushort4 o = { f2bf(v.x), f2bf(v.y), f2bf(v.z), f2bf(v.w) };
        ((ushort4*)xb)[i] = o;
    } else {
        const int i = (b - 8064) * 256 + tid;
        float4 v = ((const float4*)keys)[i];
        ushort4 o = { f2bf(v.x), f2bf(v.y), f2bf(v.z), f2bf(v.w) };
        ((ushort4*)keysb)[i] = o;
    }
}

// --------------------------- MFMA GEMM (BK=64, 2-phase pipelined) ---------
// TM in {32,64,128}; this round the big GEMMs run TM=32 for 4 blocks/CU.
template<int TM, int CMODE, int ACT, int PKMM, int BMODE>
__global__ __launch_bounds__(256) void gemm_lds(
    const unsigned short* __restrict__ A, const unsigned short* __restrict__ BT,
    const float* __restrict__ b0, const float* __restrict__ b1,
    const float* __restrict__ b2,
    void* __restrict__ Cg, void* __restrict__ Cg2,
    int M, int N, int K, int lda, int ldc, int ldc2)
{
    __shared__ unsigned short As[2][TM * 64];
    __shared__ unsigned short Bs[2][128 * 64];
    const int tid = threadIdx.x, lane = tid & 63, w = tid >> 6;
    const int l15 = lane & 15, l4 = lane >> 4;
    const int wr = w >> 1, wc = w & 1;
    constexpr int NI = (TM + 31) / 32 > 1 ? TM / 32 : 1;

    int bx = blockIdx.x, by = blockIdx.y;
    {
        const int nx = gridDim.x, nwg = nx * gridDim.y;
        if ((nwg & 7) == 0) {
            int flat = by * nx + bx;
            const int cpx = nwg >> 3;
            flat = (flat & 7) * cpx + (flat >> 3);
            bx = flat % nx; by = flat / nx;
        }
    }

    size_t aoff = 0, boff = 0, coff = 0;
    if (PKMM) {
        int z = blockIdx.z;
        aoff = (size_t)(z >> 1) * KD + (size_t)(z & 1) * HALF;
        boff = (size_t)z * NK * HALF;
        coff = (size_t)z * NK;
    }
    const int rowA0 = by * TM, rowB0 = bx * 128;

    const int sr = lane >> 3, sc = lane & 7;
    const int scg = sc ^ sr;
    const int cx = l15 & 7;

    f32x4 acc[NI][4];
#pragma unroll
    for (int i = 0; i < NI; i++)
#pragma unroll
        for (int j = 0; j < 4; j++) acc[i][j] = (f32x4){0.f, 0.f, 0.f, 0.f};

    auto STAGE = [&](int t, int buf) {
        const int k0 = t * 64;
        if (TM == 128) {
#pragma unroll
            for (int i = 0; i < 4; i++) {
                const int r0 = w * 32 + i * 8;
                ld_lds16(&A[aoff + (size_t)(rowA0 + r0 + sr) * lda + k0 + scg * 8],
                         &As[buf][r0 * 64]);
            }
        } else if (TM == 64) {
#pragma unroll
            for (int i = 0; i < 2; i++) {
                const int r0 = w * 16 + i * 8;
                ld_lds16(&A[aoff + (size_t)(rowA0 + r0 + sr) * lda + k0 + scg * 8],
                         &As[buf][r0 * 64]);
            }
        } else {
            const int r0 = w * 8;
            ld_lds16(&A[aoff + (size_t)(rowA0 + r0 + sr) * lda + k0 + scg * 8],
                     &As[buf][r0 * 64]);
        }
#pragma unroll
        for (int i = 0; i < 4; i++) {
            const int r0 = w * 32 + i * 8;
            ld_lds16(&BT[boff + (size_t)(rowB0 + r0 + sr) * K + k0 + scg * 8],
                     &Bs[buf][r0 * 64]);
        }
    };

    const int NT = K / 64;
    STAGE(0, 0);
    for (int t = 0; t < NT; ++t) {
        const int cur = t & 1;
        if (t + 1 < NT) {
            STAGE(t + 1, cur ^ 1);
            if constexpr (TM == 128)     asm volatile("s_waitcnt vmcnt(8)" ::: "memory");
            else if constexpr (TM == 64) asm volatile("s_waitcnt vmcnt(6)" ::: "memory");
            else                         asm volatile("s_waitcnt vmcnt(5)" ::: "memory");
        } else {
            asm volatile("s_waitcnt vmcnt(0)" ::: "memory");
        }
        __builtin_amdgcn_sched_barrier(0);
        __builtin_amdgcn_s_barrier();
        __builtin_amdgcn_sched_barrier(0);

        short8_t af[2][NI], bf[2][4];
#pragma unroll
        for (int h = 0; h < 2; h++) {
            const int co = ((l4 + 4 * h) ^ cx) * 8;
#pragma unroll
            for (int i = 0; i < NI; i++)
                af[h][i] = *(const short8_t*)&As[cur][(wr * (TM / 2) + i * 16 + l15) * 64 + co];
#pragma unroll
            for (int j = 0; j < 4; j++)
                bf[h][j] = *(const short8_t*)&Bs[cur][(wc * 64 + j * 16 + l15) * 64 + co];
        }
#pragma unroll
        for (int h = 0; h < 2; h++)
#pragma unroll
            for (int i = 0; i < NI; i++)
#pragma unroll
                for (int j = 0; j < 4; j++)
                    acc[i][j] = __builtin_amdgcn_mfma_f32_16x16x32_bf16(af[h][i], bf[h][j], acc[i][j], 0, 0, 0);
        __builtin_amdgcn_sched_barrier(0);
        __builtin_amdgcn_s_barrier();
        __builtin_amdgcn_sched_barrier(0);
    }

#pragma unroll
    for (int i = 0; i < NI; i++) {
#pragma unroll
        for (int j = 0; j < 4; j++) {
            const int row = rowA0 + wr * (TM / 2) + i * 16 + l4 * 4;
            const int col = rowB0 + wc * 64 + j * 16 + l15;
            float bv;
            if (PKMM) bv = 0.f;
            else if (BMODE == 0) bv = b0[col];
            else if (BMODE == 1) bv = (col < 768) ? b0[col] : (col < 1536 ? b1[col - 768] : b2[col - 1536]);
            else bv = (col < 768) ? b0[col] : b1[col - 768];
#pragma unroll
            for (int jj = 0; jj < 4; jj++) {
                float v = acc[i][j][jj] + bv;
                if (ACT == 1) v = 0.5f * v * (1.0f + erff(v * 0.70710678118654752f));
                if (CMODE == 0)
                    ((float*)Cg)[coff + (size_t)(row + jj) * ldc + col] = v;
                else if (CMODE == 1)
                    ((unsigned short*)Cg)[coff + (size_t)(row + jj) * ldc + col] = f2bf(v);
                else {
                    if (col < 768)
                        ((float*)Cg)[(size_t)(row + jj) * ldc + col] = v;
                    else
                        ((unsigned short*)Cg2)[(size_t)(row + jj) * ldc2 + (col - 768)] = f2bf(v);
                }
            }
        }
    }
}

// ----------------------------------------------------- MFMA flash attention
constexpr int AST = 72;   // bf16 elem stride

__global__ __launch_bounds__(256) void attn_mfma(const unsigned short* __restrict__ qkv,
    unsigned short* __restrict__ ctx)
{
    __shared__ unsigned short Qs[64 * AST], Ks[64 * AST], Vt[64 * AST], Ss[64 * AST];
    const int tid = threadIdx.x, lane = tid & 63, w = tid >> 6;
    const int l15 = lane & 15, l4 = lane >> 4;
    const int h = blockIdx.y, b = blockIdx.z, q0 = blockIdx.x * 64;
    const int tb0 = b * CS;

#pragma unroll
    for (int it = 0; it < 2; ++it) {
        int e = it * 256 + tid, r = e >> 3, c = e & 7;
        *(uint4*)&Qs[r * AST + c * 8] =
            *(const uint4*)&qkv[(size_t)(tb0 + q0 + r) * 2304 + h * 64 + c * 8];
    }
    f32x4 accO[4];
    float mreg[4], lreg[4];
#pragma unroll
    for (int j = 0; j < 4; j++) accO[j] = (f32x4){0.f, 0.f, 0.f, 0.f};
#pragma unroll
    for (int r = 0; r < 4; r++) { mreg[r] = -1e30f; lreg[r] = 0.f; }

    uint4 kr[2], vr[2];
    auto LOADKV = [&](int kt) {
#pragma unroll
        for (int it = 0; it < 2; ++it) {
            int e = it * 256 + tid, r = e >> 3, c = e & 7;
            kr[it] = *(const uint4*)&qkv[(size_t)(tb0 + kt * 64 + r) * 2304 + 768 + h * 64 + c * 8];
            vr[it] = *(const uint4*)&qkv[(size_t)(tb0 + kt * 64 + r) * 2304 + 1536 + h * 64 + c * 8];
        }
    };
    LOADKV(0);
    __syncthreads();
    const short8_t aq0 = *(const short8_t*)&Qs[(w * 16 + l15) * AST + l4 * 8];
    const short8_t aq1 = *(const short8_t*)&Qs[(w * 16 + l15) * AST + 32 + l4 * 8];

    for (int kt = 0; kt < 8; ++kt) {
#pragma unroll
        for (int it = 0; it < 2; ++it) {
            int e = it * 256 + tid, r = e >> 3, c = e & 7;
            *(uint4*)&Ks[r * AST + c * 8] = kr[it];
            const unsigned short* pv = (const unsigned short*)&vr[it];
            const int rc = (((r >> 3) + c) & 7) * 8 + (r & 7);
#pragma unroll
            for (int e2 = 0; e2 < 8; ++e2)
                Vt[(c * 8 + e2) * AST + rc] = pv[e2];
        }
        if (kt + 1 < 8) LOADKV(kt + 1);   // in flight across compute
        __syncthreads();

        f32x4 sc[4];
#pragma unroll
        for (int j = 0; j < 4; j++) sc[j] = (f32x4){0.f, 0.f, 0.f, 0.f};
#pragma unroll
        for (int j = 0; j < 4; j++) {
            short8_t bk0 = *(const short8_t*)&Ks[(j * 16 + l15) * AST + l4 * 8];
            short8_t bk1 = *(const short8_t*)&Ks[(j * 16 + l15) * AST + 32 + l4 * 8];
            sc[j] = __builtin_amdgcn_mfma_f32_16x16x32_bf16(aq0, bk0, sc[j], 0, 0, 0);
            sc[j] = __builtin_amdgcn_mfma_f32_16x16x32_bf16(aq1, bk1, sc[j], 0, 0, 0);
        }

        float cf[4];
#pragma unroll
        for (int r = 0; r < 4; r++) {
            float s0 = sc[0][r] * 0.125f, s1 = sc[1][r] * 0.125f;
            float s2 = sc[2][r] * 0.125f, s3 = sc[3][r] * 0.125f;
            float mt = fmaxf(fmaxf(s0, s1), fmaxf(s2, s3));
            mt = fmaxf(mt, __shfl_xor(mt, 1));
            mt = fmaxf(mt, __shfl_xor(mt, 2));
            mt = fmaxf(mt, __shfl_xor(mt, 4));
            mt = fmaxf(mt, __shfl_xor(mt, 8));
            float mo = mreg[r], mn = fmaxf(mo, mt);
            float c = __expf(mo - mn);
            mreg[r] = mn; cf[r] = c;
            float p0 = __expf(s0 - mn), p1 = __expf(s1 - mn);
            float p2 = __expf(s2 - mn), p3 = __expf(s3 - mn);
            float ps = p0 + p1 + p2 + p3;
            ps += __shfl_xor(ps, 1);
            ps += __shfl_xor(ps, 2);
            ps += __shfl_xor(ps, 4);
            ps += __shfl_xor(ps, 8);
            lreg[r] = lreg[r] * c + ps;
            const int qrow = (w * 16 + l4 * 4 + r) * AST;
            Ss[qrow + l15]      = f2bf(p0);
            Ss[qrow + 16 + l15] = f2bf(p1);
            Ss[qrow + 32 + l15] = f2bf(p2);
            Ss[qrow + 48 + l15] = f2bf(p3);
        }
#pragma unroll
        for (int j = 0; j < 4; j++) {
            accO[j][0] *= cf[0]; accO[j][1] *= cf[1];
            accO[j][2] *= cf[2]; accO[j][3] *= cf[3];
        }

        const short8_t ap0 = *(const short8_t*)&Ss[(w * 16 + l15) * AST + l4 * 8];
        const short8_t ap1 = *(const short8_t*)&Ss[(w * 16 + l15) * AST + 32 + l4 * 8];
#pragma unroll
        for (int j = 0; j < 4; j++) {
            const int d = j * 16 + l15, dc = d >> 3;
            short8_t bv0 = *(const short8_t*)&Vt[d * AST + (((l4    ) + dc) & 7) * 8];
            short8_t bv1 = *(const short8_t*)&Vt[d * AST + (((l4 + 4) + dc) & 7) * 8];
            accO[j] = __builtin_amdgcn_mfma_f32_16x16x32_bf16(ap0, bv0, accO[j], 0, 0, 0);
            accO[j] = __builtin_amdgcn_mfma_f32_16x16x32_bf16(ap1, bv1, accO[j], 0, 0, 0);
        }
        __syncthreads();   // LDS consumed; next iter may overwrite
    }

    float inv[4];
#pragma unroll
    for (int r = 0; r < 4; r++) inv[r] = 1.0f / lreg[r];
#pragma unroll
    for (int j = 0; j < 4; j++)
#pragma unroll
        for (int r = 0; r < 4; r++)
            ctx[(size_t)(tb0 + q0 + w * 16 + l4 * 4 + r) * CD + h * 64 + j * 16 + l15] =
                f2bf(accO[j][r] * inv[r]);
}

// ----------------------------------------------------------- layernorm ----
__global__ __launch_bounds__(256) void ln_kernel(float* __restrict__ out,
    unsigned short* __restrict__ outb,
    const float* __restrict__ a, int lda,
    const float* __restrict__ b2,
    const float* __restrict__ g, const float* __restrict__ bb)
{
    const int t = blockIdx.x, tid = threadIdx.x;
    __shared__ float buf[CD];
    __shared__ float red[256];
    float l = 0.f;
    for (int d = tid; d < CD; d += 256) {
        float v = a[(size_t)t * lda + d];
        if (b2) v += b2[(size_t)t * CD + d];
        buf[d] = v; l += v;
    }
    red[tid] = l; __syncthreads();
    for (int o = 128; o > 0; o >>= 1) { if (tid < o) red[tid] += red[tid + o]; __syncthreads(); }
    const float mean = red[0] * (1.0f / CD); __syncthreads();
    float l2 = 0.f;
    for (int d = tid; d < CD; d += 256) { float dd = buf[d] - mean; l2 += dd * dd; }
    red[tid] = l2; __syncthreads();
    for (int o = 128; o > 0; o >>= 1) { if (tid < o) red[tid] += red[tid + o]; __syncthreads(); }
    const float inv = rsqrtf(red[0] * (1.0f / CD) + 1e-12f);
    for (int d = tid; d < CD; d += 256) {
        float v = (buf[d] - mean) * inv * g[d] + bb[d];
        out[(size_t)t * CD + d] = v;
        if (outb) outb[(size_t)t * CD + d] = f2bf(v);
    }
}

// --------------------------------------------- fused PKM top-k (both stages)
__device__ const unsigned char CCNT[32] = {32,16,10,8,6,5,4,4,3,3,2,2,2,2,2,2,
                                           1,1,1,1,1,1,1,1,1,1,1,1,1,1,1,1};

__global__ __launch_bounds__(128) void pkm_topk_kernel(const float* __restrict__ sc,
    float* __restrict__ w, int* __restrict__ ind)
{
    const int gid = blockIdx.x;            // t*PH + h
    const int tid = threadIdx.x;
    __shared__ float sv[256];
    __shared__ int   si_[256];
    __shared__ float cv[128];
    __shared__ int   ci[128];

    const float* s = sc + (size_t)gid * 256;
    sv[tid] = s[tid];             si_[tid] = tid;
    sv[tid + 128] = s[tid + 128]; si_[tid + 128] = tid;
    __syncthreads();

    for (int k = 2; k <= 128; k <<= 1) {
        for (int j = k >> 1; j > 0; j >>= 1) {
            const int hh = tid >> 6, p = tid & 63;
            const int i = ((p & ~(j - 1)) << 1) | (p & (j - 1));
            const int l = i | j;
            const int bi_ = hh * 128 + i, bl = hh * 128 + l;
            float av = sv[bi_], bv2 = sv[bl];
            int   ai = si_[bi_], bx = si_[bl];
            const bool agtb = (av > bv2) || (av == bv2 && ai < bx);
            const bool desc = ((i & k) == 0);
            if (agtb != desc) { sv[bi_] = bv2; sv[bl] = av; si_[bi_] = bx; si_[bl] = ai; }
            __syncthreads();
        }
    }

    {
        float val; int fi;
        if (tid < 119) {
            int tt = tid, ii = 0;
            while (tt >= (int)CCNT[ii]) { tt -= CCNT[ii]; ii++; }
            val = sv[ii] + sv[128 + tt];
            fi = ii * 32 + tt;
        } else { val = -3.0e38f; fi = 0x7FFFFFF; }
        cv[tid] = val; ci[tid] = fi;
    }
    __syncthreads();

    for (int k = 2; k <= 128; k <<= 1) {
        for (int j = k >> 1; j > 0; j >>= 1) {
            if (tid < 64) {
                const int p = tid;
                const int i = ((p & ~(j - 1)) << 1) | (p & (j - 1));
                const int l = i | j;
                float av = cv[i], bv2 = cv[l];
                int   ai = ci[i], bx = ci[l];
                const bool agtb = (av > bv2) || (av == bv2 && ai < bx);
                const bool desc = ((i & k) == 0);
                if (agtb != desc) { cv[i] = bv2; cv[l] = av; ci[i] = bx; ci[l] = ai; }
            }
            __syncthreads();
        }
    }

    if (tid < 32) {
        const float mx = cv[0];
        float e = __expf(cv[tid] - mx);
        float s2 = e;
        for (int o = 16; o > 0; o >>= 1) s2 += __shfl_xor(s2, o);
        const int fi = ci[tid];
        const int ii = fi >> 5, jj = fi & 31;
        w[(size_t)gid * KNN + tid] = e / s2;
        ind[(size_t)gid * KNN + tid] = si_[ii] * NK + si_[128 + jj];
    }
}

// ----------------------------------- fused PKM gather + residual + LN2 ----
// bf16 fallback version (256 threads, 3 dims each)
__global__ __launch_bounds__(256) void ln2_pkm_kernel(
    const float* __restrict__ dense, const float* __restrict__ attnf,
    const float* __restrict__ wgt, const int* __restrict__ ind,
    const unsigned short* __restrict__ valb,
    const float* __restrict__ g, const float* __restrict__ bb,
    float* __restrict__ out)
{
    const int t = blockIdx.x, tid = threadIdx.x;
    __shared__ float ws[PH * KNN];
    __shared__ int   is[PH * KNN];
    __shared__ float red[256];
    if (tid < PH * KNN) {
        ws[tid] = wgt[(size_t)t * PH * KNN + tid];
        is[tid] = ind[(size_t)t * PH * KNN + tid];
    }
    __syncthreads();
    float a0 = 0.f, a1 = 0.f, a2 = 0.f;
#pragma unroll 4
    for (int i = 0; i < PH * KNN; i++) {
        const unsigned short* vr = valb + (size_t)is[i] * CD;
        const float wv = ws[i];
        a0 = fmaf(wv, bf2f(vr[tid]), a0);
        a1 = fmaf(wv, bf2f(vr[tid + 256]), a1);
        a2 = fmaf(wv, bf2f(vr[tid + 512]), a2);
    }
    const size_t base = (size_t)t * CD;
    float v0 = a0 + dense[base + tid]       + attnf[base + tid];
    float v1 = a1 + dense[base + tid + 256] + attnf[base + tid + 256];
    float v2 = a2 + dense[base + tid + 512] + attnf[base + tid + 512];

    red[tid] = v0 + v1 + v2; __syncthreads();
    for (int o = 128; o > 0; o >>= 1) { if (tid < o) red[tid] += red[tid + o]; __syncthreads(); }
    const float mean = red[0] * (1.0f / CD); __syncthreads();
    float d0 = v0 - mean, d1 = v1 - mean, d2 = v2 - mean;
    red[tid] = d0 * d0 + d1 * d1 + d2 * d2; __syncthreads();
    for (int o = 128; o > 0; o >>= 1) { if (tid < o) red[tid] += red[tid + o]; __syncthreads(); }
    const float inv = rsqrtf(red[0] * (1.0f / CD) + 1e-12f);
    out[base + tid]       = d0 * inv * g[tid]       + bb[tid];
    out[base + tid + 256] = d1 * inv * g[tid + 256] + bb[tid + 256];
    out[base + tid + 512] = d2 * inv * g[tid + 512] + bb[tid + 512];
}

#if HAS_FP8
// fp8 version: 192 threads, 4 dims each (u32-aligned fp8 reads)
__global__ __launch_bounds__(192) void ln2_pkm_f8(
    const float* __restrict__ dense, const float* __restrict__ attnf,
    const float* __restrict__ wgt, const int* __restrict__ ind,
    const unsigned char* __restrict__ valf8,
    const float* __restrict__ g, const float* __restrict__ bb,
    float* __restrict__ out)
{
    const int t = blockIdx.x, tid = threadIdx.x;
    __shared__ float ws[PH * KNN];
    __shared__ int   is[PH * KNN];
    __shared__ float red[2];
    if (tid < PH * KNN) {
        ws[tid] = wgt[(size_t)t * PH * KNN + tid];
        is[tid] = ind[(size_t)t * PH * KNN + tid];
    }
    __syncthreads();
    float a0 = 0.f, a1 = 0.f, a2 = 0.f, a3 = 0.f;
#pragma unroll 4
    for (int i = 0; i < PH * KNN; i++) {
        unsigned pv = *(const unsigned*)(valf8 + (size_t)is[i] * CD + tid * 4);
        const float wv = ws[i];
        f32x2 lo = __builtin_amdgcn_cvt_pk_f32_fp8(pv, false);
        f32x2 hi = __builtin_amdgcn_cvt_pk_f32_fp8(pv, true);
        a0 = fmaf(wv, lo.x, a0);
        a1 = fmaf(wv, lo.y, a1);
        a2 = fmaf(wv, hi.x, a2);
        a3 = fmaf(wv, hi.y, a3);
    }
    const size_t base = (size_t)t * CD + tid * 4;
    float4 dv = *(const float4*)(dense + base);
    float4 av = *(const float4*)(attnf + base);
    float v0 = a0 + dv.x + av.x, v1 = a1 + dv.y + av.y;
    float v2 = a2 + dv.z + av.z, v3 = a3 + dv.w + av.w;

    __shared__ float rbuf[192];
    rbuf[tid] = v0 + v1 + v2 + v3; __syncthreads();
    if (tid < 64) {
        float s = rbuf[tid] + rbuf[tid + 64] + rbuf[tid + 128];
        s += __shfl_xor(s, 32); s += __shfl_xor(s, 16); s += __shfl_xor(s, 8);
        s += __shfl_xor(s, 4);  s += __shfl_xor(s, 2);  s += __shfl_xor(s, 1);
        if (tid == 0) red[0] = s;
    }
    __syncthreads();
    const float mean = red[0] * (1.0f / CD);
    float d0 = v0 - mean, d1 = v1 - mean, d2 = v2 - mean, d3 = v3 - mean;
    rbuf[tid] = d0 * d0 + d1 * d1 + d2 * d2 + d3 * d3; __syncthreads();
    if (tid < 64) {
        float s = rbuf[tid] + rbuf[tid + 64] + rbuf[tid + 128];
        s += __shfl_xor(s, 32); s += __shfl_xor(s, 16); s += __shfl_xor(s, 8);
        s += __shfl_xor(s, 4);  s += __shfl_xor(s, 2);  s += __shfl_xor(s, 1);
        if (tid == 0) red[1] = s;
    }
    __syncthreads();
    const float inv = rsqrtf(red[1] * (1.0f / CD) + 1e-12f);
    float4 gv = *(const float4*)(g + tid * 4);
    float4 bv = *(const float4*)(bb + tid * 4);
    float4 o;
    o.x = d0 * inv * gv.x + bv.x;
    o.y = d1 * inv * gv.y + bv.y;
    o.z = d2 * inv * gv.z + bv.z;
    o.w = d3 * inv * gv.w + bv.w;
    *(float4*)(out + base) = o;
}
#endif

// ------------------------------------------------------------- launch -----
extern "C" void kernel_launch(void* const* d_in, const int* in_sizes, int n_in,
                              void* d_out, int out_size, void* d_ws, size_t ws_size,
                              hipStream_t stream)
{
    const float* x      = (const float*)d_in[0];
    const float* Wq     = (const float*)d_in[1];
    const float* bq     = (const float*)d_in[2];
    const float* Wk     = (const float*)d_in[3];
    const float* bk     = (const float*)d_in[4];
    const float* Wv     = (const float*)d_in[5];
    const float* bv     = (const float*)d_in[6];
    const float* Wo     = (const float*)d_in[7];
    const float* bo     = (const float*)d_in[8];
    const float* ln1_g  = (const float*)d_in[9];
    const float* ln1_b  = (const float*)d_in[10];
    const float* Wi     = (const float*)d_in[11];
    const float* bi     = (const float*)d_in[12];
    const float* Wd     = (const float*)d_in[13];
    const float* bd     = (const float*)d_in[14];
    const float* ln2_g  = (const float*)d_in[15];
    const float* ln2_b  = (const float*)d_in[16];
    const float* Wpq    = (const float*)d_in[17];
    const float* bpq    = (const float*)d_in[18];
    const float* keys   = (const float*)d_in[19];
    const float* values = (const float*)d_in[20];

    char* W = (char*)d_ws;
    unsigned short* qkvb  = (unsigned short*)(W + 0);
    float*          sbuf  = (float*)(W + 0);
    float*          attnf = (float*)(W + 9437184);
    unsigned short* ctxb  = (unsigned short*)(W + 15728640);
    unsigned short* interb= (unsigned short*)(W + 15728640);
    float*          wgt   = (float*)(W + 15728640);
    int*            ind   = (int*)(W + 16777216);
    unsigned short* xb    = (unsigned short*)(W + 28311552);
    float*          woout = (float*)(W + 28311552);
    float*          dense = (float*)(W + 28311552);
    unsigned short* attnb = (unsigned short*)(W + 34603008);
    unsigned short* pqb   = (unsigned short*)(W + 37748736);
    unsigned short* keysb = (unsigned short*)(W + 46137344);
    unsigned short* wt    = (unsigned short*)(W + 46661632);
    void*           valq  = (void*)(W + 46661632);   // fp8 (12.6MB) or bf16 (25.2MB)

    const dim3 blk(256);
    const size_t WOFF = 589824;   // 768*768

    // fused prep: weight transposes + x/keys bf16 conversion
    prep_kernel<<<8320, blk, 0, stream>>>(Wq, Wk, Wv, Wo, Wi, Wd, Wpq, wt,
                                          x, xb, keys, keysb);

    // merged QKV projection (TM=32 -> 1152 blocks, 4/CU LDS-capped)
    gemm_lds<32, 1, 0, 0, 1><<<dim3(18, 64), blk, 0, stream>>>(
        xb, wt, bq, bk, bv, qkvb, nullptr, CT, 2304, CD, CD, 2304, 0);

    // flash attention (MFMA, T14 dbuf)
    attn_mfma<<<dim3(8, 12, 4), blk, 0, stream>>>(qkvb, ctxb);

    // output projection + LN1 (TM=32 -> 384 blocks)
    gemm_lds<32, 0, 0, 0, 0><<<dim3(6, 64), blk, 0, stream>>>(
        ctxb, wt + 3 * WOFF, bo, nullptr, nullptr, woout, nullptr, CT, CD, CD, CD, CD, 0);
    ln_kernel<<<CT, blk, 0, stream>>>(attnf, attnb, woout, CD, x, ln1_g, ln1_b);

    // FFN up (GELU, bf16 out)  (TM=32 -> 1536 blocks)
    gemm_lds<32, 1, 1, 0, 0><<<dim3(24, 64), blk, 0, stream>>>(
        attnb, wt + 4 * WOFF, bi, nullptr, nullptr, interb, nullptr, CT, CFF, CD, CD, CFF, 0);

    // merged FFN down + PKM query proj (TM=32 -> 1408 blocks)
    gemm_lds<32, 2, 0, 0, 2><<<dim3(22, 64), blk, 0, stream>>>(
        interb, wt + 4 * WOFF + 2359296, bd, bpq, nullptr, dense, pqb, CT, 2816, CFF, CFF, CD, 2048);

    // values -> fp8/bf16 (into dead wt region)
#if HAS_FP8
    cvt_fp8x4<<<2048, blk, 0, stream>>>(values, (unsigned*)valq, (NK * NK * CD) / 4);
#else
    cvt_bf16x4<<<2048, blk, 0, stream>>>(values, (unsigned short*)valq, (NK * NK * CD) / 4);
#endif

    // PKM scores: 8 batched GEMMs (TM=32 -> 512 blocks, 2/CU)
    gemm_lds<32, 0, 0, 1, 0><<<dim3(1, 64, 8), blk, 0, stream>>>(
        pqb, keysb, nullptr, nullptr, nullptr, sbuf, nullptr, CT, NK, HALF, 2048, PH * 2 * NK, 0);

    // fused two-stage top-k + softmax
    pkm_topk_kernel<<<CT * PH, dim3(128), 0, stream>>>(sbuf, wgt, ind);

    // fused gather + residual + LN2
#if HAS_FP8
    ln2_pkm_f8<<<CT, dim3(192), 0, stream>>>(dense, attnf, wgt, ind,
        (const unsigned char*)valq, ln2_g, ln2_b, (float*)d_out);
#else
    ln2_pkm_kernel<<<CT, blk, 0, stream>>>(dense, attnf, wgt, ind,
        (const unsigned short*)valq, ln2_g, ln2_b, (float*)d_out);
#endif
}

// Round 12
// 246.975 us; speedup vs baseline: 1.1858x; 1.1858x over previous
//
#include <hip/hip_runtime.h>
#include <math.h>

// Problem constants
constexpr int CB = 4, CS = 512, CD = 768, CFF = 3072, CH = 12, CHD = 64;
constexpr int CT = CB * CS;            // 2048 tokens
constexpr int PH = 4, KD = 512, NK = 128, KNN = 32, HALF = 256;

typedef __attribute__((ext_vector_type(8))) short short8_t;   // 8 bf16 (4 VGPRs)
typedef __attribute__((ext_vector_type(4))) float f32x4;      // MFMA accumulator

__device__ __forceinline__ unsigned short f2bf(float f) {
    unsigned int u = __float_as_uint(f);
    return (unsigned short)((u + 0x7FFF + ((u >> 16) & 1)) >> 16);  // RNE
}
__device__ __forceinline__ float bf2f(unsigned short h) {
    return __uint_as_float(((unsigned)h) << 16);
}

// async global->LDS, 16B per lane; LDS dest = wave-uniform base + lane*16
__device__ __forceinline__ void ld_lds16(const unsigned short* g, unsigned short* l) {
    __builtin_amdgcn_global_load_lds(
        (const __attribute__((address_space(1))) void*)g,
        (__attribute__((address_space(3))) void*)l, 16, 0, 0);
}

// ------------------------------------------------------------ fp32->bf16 --
__global__ __launch_bounds__(256) void cvt_bf16x4(const float* __restrict__ in,
    unsigned short* __restrict__ out, int n4)
{
    for (int i = blockIdx.x * 256 + threadIdx.x; i < n4; i += gridDim.x * 256) {
        float4 v = ((const float4*)in)[i];
        ushort4 o = { f2bf(v.x), f2bf(v.y), f2bf(v.z), f2bf(v.w) };
        ((ushort4*)out)[i] = o;
    }
}

// ------------------------- fused prep: weight transposes + x/keys cvt -----
__global__ __launch_bounds__(256) void prep_kernel(
    const float* __restrict__ Wq, const float* __restrict__ Wk,
    const float* __restrict__ Wv, const float* __restrict__ Wo,
    const float* __restrict__ Wi, const float* __restrict__ Wd,
    const float* __restrict__ Wpq, unsigned short* __restrict__ wt,
    const float* __restrict__ x, unsigned short* __restrict__ xb,
    const float* __restrict__ keys, unsigned short* __restrict__ keysb)
{
    const int b = blockIdx.x, tid = threadIdx.x;
    if (b < 6528) {
        __shared__ unsigned short ts[32][72];   // [n][k], 16B-aligned rows
        const float* W; unsigned short* WT; int K, N, tile;
        if (b < 1152) {
            int z = b / 288; tile = b - z * 288;
            W = (z == 0) ? Wq : (z == 1) ? Wk : (z == 2) ? Wv : Wo;
            WT = wt + (size_t)z * 589824; K = 768; N = 768;
        } else if (b < 2304) {
            tile = b - 1152; W = Wi; WT = wt + 4 * 589824; K = 768; N = 3072;
        } else if (b < 3456) {
            tile = b - 2304; W = Wd; WT = wt + 4 * 589824 + 2359296; K = 3072; N = 768;
        } else {
            tile = b - 3456; W = Wpq; WT = wt + 4 * 589824 + 2 * 2359296; K = 3072; N = 2048;
        }
        const int nx = N >> 5;
        const int n0 = (tile % nx) * 32, k0 = (tile / nx) * 64;
        const int c = tid & 31, rr = tid >> 5;
#pragma unroll
        for (int i = 0; i < 8; i++) {
            int r = rr + i * 8;
            ts[c][r] = f2bf(W[(size_t)(k0 + r) * N + n0 + c]);
        }
        __syncthreads();
        const int nn = tid >> 3, kc = tid & 7;
        uint4 v = *(const uint4*)&ts[nn][kc * 8];
        *(uint4*)&WT[(size_t)(n0 + nn) * K + k0 + kc * 8] = v;
    } else if (b < 8064) {
        const int i = (b - 6528) * 256 + tid;
        float4 v = ((const float4*)x)[i];
        ushort4 o = { f2bf(v.x), f2bf(v.y), f2bf(v.z), f2bf(v.w) };
        ((ushort4*)xb)[i] = o;
    } else {
        const int i = (b - 8064) * 256 + tid;
        float4 v = ((const float4*)keys)[i];
        ushort4 o = { f2bf(v.x), f2bf(v.y), f2bf(v.z), f2bf(v.w) };
        ((ushort4*)keysb)[i] = o;
    }
}

// --------------------------- MFMA GEMM (BK=64, 2-phase pipelined) ---------
// C[M,N] = A[M,K] @ B[K,N] + bias; A bf16 [M][lda], BT bf16 [N][K].
// Double-buffered LDS, BK=64; STAGE(t+1) issued before compute(t); counted
// s_waitcnt keeps next-tile loads in flight across the raw s_barrier.
// Both-sides XOR swizzle (chunk ^= row&7) -> 2-way bank aliasing (free).
// XCD-aware bijective block swizzle when grid%8==0 (T1). TM in {32,64,128}.
template<int TM, int CMODE, int ACT, int PKMM, int BMODE>
__global__ __launch_bounds__(256) void gemm_lds(
    const unsigned short* __restrict__ A, const unsigned short* __restrict__ BT,
    const float* __restrict__ b0, const float* __restrict__ b1,
    const float* __restrict__ b2,
    void* __restrict__ Cg, void* __restrict__ Cg2,
    int M, int N, int K, int lda, int ldc, int ldc2)
{
    __shared__ unsigned short As[2][TM * 64];
    __shared__ unsigned short Bs[2][128 * 64];
    const int tid = threadIdx.x, lane = tid & 63, w = tid >> 6;
    const int l15 = lane & 15, l4 = lane >> 4;
    const int wr = w >> 1, wc = w & 1;
    constexpr int NI = (TM + 31) / 32 > 1 ? TM / 32 : 1;

    int bx = blockIdx.x, by = blockIdx.y;
    {
        const int nx = gridDim.x, nwg = nx * gridDim.y;
        if ((nwg & 7) == 0) {
            int flat = by * nx + bx;
            const int cpx = nwg >> 3;
            flat = (flat & 7) * cpx + (flat >> 3);
            bx = flat % nx; by = flat / nx;
        }
    }

    size_t aoff = 0, boff = 0, coff = 0;
    if (PKMM) {
        int z = blockIdx.z;
        aoff = (size_t)(z >> 1) * KD + (size_t)(z & 1) * HALF;
        boff = (size_t)z * NK * HALF;
        coff = (size_t)z * NK;
    }
    const int rowA0 = by * TM, rowB0 = bx * 128;

    const int sr = lane >> 3, sc = lane & 7;
    const int scg = sc ^ sr;
    const int cx = l15 & 7;

    f32x4 acc[NI][4];
#pragma unroll
    for (int i = 0; i < NI; i++)
#pragma unroll
        for (int j = 0; j < 4; j++) acc[i][j] = (f32x4){0.f, 0.f, 0.f, 0.f};

    auto STAGE = [&](int t, int buf) {
        const int k0 = t * 64;
        if (TM == 128) {
#pragma unroll
            for (int i = 0; i < 4; i++) {
                const int r0 = w * 32 + i * 8;
                ld_lds16(&A[aoff + (size_t)(rowA0 + r0 + sr) * lda + k0 + scg * 8],
                         &As[buf][r0 * 64]);
            }
        } else if (TM == 64) {
#pragma unroll
            for (int i = 0; i < 2; i++) {
                const int r0 = w * 16 + i * 8;
                ld_lds16(&A[aoff + (size_t)(rowA0 + r0 + sr) * lda + k0 + scg * 8],
                         &As[buf][r0 * 64]);
            }
        } else {
            const int r0 = w * 8;
            ld_lds16(&A[aoff + (size_t)(rowA0 + r0 + sr) * lda + k0 + scg * 8],
                     &As[buf][r0 * 64]);
        }
#pragma unroll
        for (int i = 0; i < 4; i++) {
            const int r0 = w * 32 + i * 8;
            ld_lds16(&BT[boff + (size_t)(rowB0 + r0 + sr) * K + k0 + scg * 8],
                     &Bs[buf][r0 * 64]);
        }
    };

    const int NT = K / 64;
    STAGE(0, 0);
    for (int t = 0; t < NT; ++t) {
        const int cur = t & 1;
        if (t + 1 < NT) {
            STAGE(t + 1, cur ^ 1);
            if constexpr (TM == 128)     asm volatile("s_waitcnt vmcnt(8)" ::: "memory");
            else if constexpr (TM == 64) asm volatile("s_waitcnt vmcnt(6)" ::: "memory");
            else                         asm volatile("s_waitcnt vmcnt(5)" ::: "memory");
        } else {
            asm volatile("s_waitcnt vmcnt(0)" ::: "memory");
        }
        __builtin_amdgcn_sched_barrier(0);
        __builtin_amdgcn_s_barrier();
        __builtin_amdgcn_sched_barrier(0);

        short8_t af[2][NI], bf[2][4];
#pragma unroll
        for (int h = 0; h < 2; h++) {
            const int co = ((l4 + 4 * h) ^ cx) * 8;
#pragma unroll
            for (int i = 0; i < NI; i++)
                af[h][i] = *(const short8_t*)&As[cur][(wr * (TM / 2) + i * 16 + l15) * 64 + co];
#pragma unroll
            for (int j = 0; j < 4; j++)
                bf[h][j] = *(const short8_t*)&Bs[cur][(wc * 64 + j * 16 + l15) * 64 + co];
        }
#pragma unroll
        for (int h = 0; h < 2; h++)
#pragma unroll
            for (int i = 0; i < NI; i++)
#pragma unroll
                for (int j = 0; j < 4; j++)
                    acc[i][j] = __builtin_amdgcn_mfma_f32_16x16x32_bf16(af[h][i], bf[h][j], acc[i][j], 0, 0, 0);
        __builtin_amdgcn_sched_barrier(0);
        __builtin_amdgcn_s_barrier();
        __builtin_amdgcn_sched_barrier(0);
    }

#pragma unroll
    for (int i = 0; i < NI; i++) {
#pragma unroll
        for (int j = 0; j < 4; j++) {
            const int row = rowA0 + wr * (TM / 2) + i * 16 + l4 * 4;
            const int col = rowB0 + wc * 64 + j * 16 + l15;
            float bv;
            if (PKMM) bv = 0.f;
            else if (BMODE == 0) bv = b0[col];
            else if (BMODE == 1) bv = (col < 768) ? b0[col] : (col < 1536 ? b1[col - 768] : b2[col - 1536]);
            else bv = (col < 768) ? b0[col] : b1[col - 768];
#pragma unroll
            for (int jj = 0; jj < 4; jj++) {
                float v = acc[i][j][jj] + bv;
                if (ACT == 1) v = 0.5f * v * (1.0f + erff(v * 0.70710678118654752f));
                if (CMODE == 0)
                    ((float*)Cg)[coff + (size_t)(row + jj) * ldc + col] = v;
                else if (CMODE == 1)
                    ((unsigned short*)Cg)[coff + (size_t)(row + jj) * ldc + col] = f2bf(v);
                else {
                    if (col < 768)
                        ((float*)Cg)[(size_t)(row + jj) * ldc + col] = v;
                    else
                        ((unsigned short*)Cg2)[(size_t)(row + jj) * ldc2 + (col - 768)] = f2bf(v);
                }
            }
        }
    }
}

// ----------------------------------------------------- MFMA flash attention
constexpr int AST = 72;   // bf16 elem stride

__global__ __launch_bounds__(256) void attn_mfma(const unsigned short* __restrict__ qkv,
    unsigned short* __restrict__ ctx)
{
    __shared__ unsigned short Qs[64 * AST], Ks[64 * AST], Vt[64 * AST], Ss[64 * AST];
    const int tid = threadIdx.x, lane = tid & 63, w = tid >> 6;
    const int l15 = lane & 15, l4 = lane >> 4;
    const int h = blockIdx.y, b = blockIdx.z, q0 = blockIdx.x * 64;
    const int tb0 = b * CS;

#pragma unroll
    for (int it = 0; it < 2; ++it) {
        int e = it * 256 + tid, r = e >> 3, c = e & 7;
        *(uint4*)&Qs[r * AST + c * 8] =
            *(const uint4*)&qkv[(size_t)(tb0 + q0 + r) * 2304 + h * 64 + c * 8];
    }
    f32x4 accO[4];
    float mreg[4], lreg[4];
#pragma unroll
    for (int j = 0; j < 4; j++) accO[j] = (f32x4){0.f, 0.f, 0.f, 0.f};
#pragma unroll
    for (int r = 0; r < 4; r++) { mreg[r] = -1e30f; lreg[r] = 0.f; }
    __syncthreads();
    const short8_t aq0 = *(const short8_t*)&Qs[(w * 16 + l15) * AST + l4 * 8];
    const short8_t aq1 = *(const short8_t*)&Qs[(w * 16 + l15) * AST + 32 + l4 * 8];

    for (int kt = 0; kt < 8; ++kt) {
        __syncthreads();
#pragma unroll
        for (int it = 0; it < 2; ++it) {
            int e = it * 256 + tid, r = e >> 3, c = e & 7;
            *(uint4*)&Ks[r * AST + c * 8] =
                *(const uint4*)&qkv[(size_t)(tb0 + kt * 64 + r) * 2304 + 768 + h * 64 + c * 8];
            uint4 vv = *(const uint4*)&qkv[(size_t)(tb0 + kt * 64 + r) * 2304 + 1536 + h * 64 + c * 8];
            const unsigned short* pv = (const unsigned short*)&vv;
            const int rc = (((r >> 3) + c) & 7) * 8 + (r & 7);
#pragma unroll
            for (int e2 = 0; e2 < 8; ++e2)
                Vt[(c * 8 + e2) * AST + rc] = pv[e2];
        }
        __syncthreads();

        f32x4 sc[4];
#pragma unroll
        for (int j = 0; j < 4; j++) sc[j] = (f32x4){0.f, 0.f, 0.f, 0.f};
#pragma unroll
        for (int j = 0; j < 4; j++) {
            short8_t bk0 = *(const short8_t*)&Ks[(j * 16 + l15) * AST + l4 * 8];
            short8_t bk1 = *(const short8_t*)&Ks[(j * 16 + l15) * AST + 32 + l4 * 8];
            sc[j] = __builtin_amdgcn_mfma_f32_16x16x32_bf16(aq0, bk0, sc[j], 0, 0, 0);
            sc[j] = __builtin_amdgcn_mfma_f32_16x16x32_bf16(aq1, bk1, sc[j], 0, 0, 0);
        }

        float cf[4];
#pragma unroll
        for (int r = 0; r < 4; r++) {
            float s0 = sc[0][r] * 0.125f, s1 = sc[1][r] * 0.125f;
            float s2 = sc[2][r] * 0.125f, s3 = sc[3][r] * 0.125f;
            float mt = fmaxf(fmaxf(s0, s1), fmaxf(s2, s3));
            mt = fmaxf(mt, __shfl_xor(mt, 1));
            mt = fmaxf(mt, __shfl_xor(mt, 2));
            mt = fmaxf(mt, __shfl_xor(mt, 4));
            mt = fmaxf(mt, __shfl_xor(mt, 8));
            float mo = mreg[r], mn = fmaxf(mo, mt);
            float c = __expf(mo - mn);
            mreg[r] = mn; cf[r] = c;
            float p0 = __expf(s0 - mn), p1 = __expf(s1 - mn);
            float p2 = __expf(s2 - mn), p3 = __expf(s3 - mn);
            float ps = p0 + p1 + p2 + p3;
            ps += __shfl_xor(ps, 1);
            ps += __shfl_xor(ps, 2);
            ps += __shfl_xor(ps, 4);
            ps += __shfl_xor(ps, 8);
            lreg[r] = lreg[r] * c + ps;
            const int qrow = (w * 16 + l4 * 4 + r) * AST;
            Ss[qrow + l15]      = f2bf(p0);
            Ss[qrow + 16 + l15] = f2bf(p1);
            Ss[qrow + 32 + l15] = f2bf(p2);
            Ss[qrow + 48 + l15] = f2bf(p3);
        }
#pragma unroll
        for (int j = 0; j < 4; j++) {
            accO[j][0] *= cf[0]; accO[j][1] *= cf[1];
            accO[j][2] *= cf[2]; accO[j][3] *= cf[3];
        }

        const short8_t ap0 = *(const short8_t*)&Ss[(w * 16 + l15) * AST + l4 * 8];
        const short8_t ap1 = *(const short8_t*)&Ss[(w * 16 + l15) * AST + 32 + l4 * 8];
#pragma unroll
        for (int j = 0; j < 4; j++) {
            const int d = j * 16 + l15, dc = d >> 3;
            short8_t bv0 = *(const short8_t*)&Vt[d * AST + (((l4    ) + dc) & 7) * 8];
            short8_t bv1 = *(const short8_t*)&Vt[d * AST + (((l4 + 4) + dc) & 7) * 8];
            accO[j] = __builtin_amdgcn_mfma_f32_16x16x32_bf16(ap0, bv0, accO[j], 0, 0, 0);
            accO[j] = __builtin_amdgcn_mfma_f32_16x16x32_bf16(ap1, bv1, accO[j], 0, 0, 0);
        }
    }

    float inv[4];
#pragma unroll
    for (int r = 0; r < 4; r++) inv[r] = 1.0f / lreg[r];
#pragma unroll
    for (int j = 0; j < 4; j++)
#pragma unroll
        for (int r = 0; r < 4; r++)
            ctx[(size_t)(tb0 + q0 + w * 16 + l4 * 4 + r) * CD + h * 64 + j * 16 + l15] =
                f2bf(accO[j][r] * inv[r]);
}

// ----------------------------------------------------------- layernorm ----
__global__ __launch_bounds__(256) void ln_kernel(float* __restrict__ out,
    unsigned short* __restrict__ outb,
    const float* __restrict__ a, int lda,
    const float* __restrict__ b2,
    const float* __restrict__ g, const float* __restrict__ bb)
{
    const int t = blockIdx.x, tid = threadIdx.x;
    __shared__ float buf[CD];
    __shared__ float red[256];
    float l = 0.f;
    for (int d = tid; d < CD; d += 256) {
        float v = a[(size_t)t * lda + d];
        if (b2) v += b2[(size_t)t * CD + d];
        buf[d] = v; l += v;
    }
    red[tid] = l; __syncthreads();
    for (int o = 128; o > 0; o >>= 1) { if (tid < o) red[tid] += red[tid + o]; __syncthreads(); }
    const float mean = red[0] * (1.0f / CD); __syncthreads();
    float l2 = 0.f;
    for (int d = tid; d < CD; d += 256) { float dd = buf[d] - mean; l2 += dd * dd; }
    red[tid] = l2; __syncthreads();
    for (int o = 128; o > 0; o >>= 1) { if (tid < o) red[tid] += red[tid + o]; __syncthreads(); }
    const float inv = rsqrtf(red[0] * (1.0f / CD) + 1e-12f);
    for (int d = tid; d < CD; d += 256) {
        float v = (buf[d] - mean) * inv * g[d] + bb[d];
        out[(size_t)t * CD + d] = v;
        if (outb) outb[(size_t)t * CD + d] = f2bf(v);
    }
}

// --------------------------------------------- fused PKM top-k (both stages)
__device__ const unsigned char CCNT[32] = {32,16,10,8,6,5,4,4,3,3,2,2,2,2,2,2,
                                           1,1,1,1,1,1,1,1,1,1,1,1,1,1,1,1};

__global__ __launch_bounds__(128) void pkm_topk_kernel(const float* __restrict__ sc,
    float* __restrict__ w, int* __restrict__ ind)
{
    const int gid = blockIdx.x;            // t*PH + h
    const int tid = threadIdx.x;
    __shared__ float sv[256];
    __shared__ int   si_[256];
    __shared__ float cv[128];
    __shared__ int   ci[128];

    const float* s = sc + (size_t)gid * 256;
    sv[tid] = s[tid];             si_[tid] = tid;
    sv[tid + 128] = s[tid + 128]; si_[tid + 128] = tid;
    __syncthreads();

    for (int k = 2; k <= 128; k <<= 1) {
        for (int j = k >> 1; j > 0; j >>= 1) {
            const int hh = tid >> 6, p = tid & 63;
            const int i = ((p & ~(j - 1)) << 1) | (p & (j - 1));
            const int l = i | j;
            const int bi_ = hh * 128 + i, bl = hh * 128 + l;
            float av = sv[bi_], bv2 = sv[bl];
            int   ai = si_[bi_], bx = si_[bl];
            const bool agtb = (av > bv2) || (av == bv2 && ai < bx);
            const bool desc = ((i & k) == 0);
            if (agtb != desc) { sv[bi_] = bv2; sv[bl] = av; si_[bi_] = bx; si_[bl] = ai; }
            __syncthreads();
        }
    }

    {
        float val; int fi;
        if (tid < 119) {
            int tt = tid, ii = 0;
            while (tt >= (int)CCNT[ii]) { tt -= CCNT[ii]; ii++; }
            val = sv[ii] + sv[128 + tt];
            fi = ii * 32 + tt;
        } else { val = -3.0e38f; fi = 0x7FFFFFF; }
        cv[tid] = val; ci[tid] = fi;
    }
    __syncthreads();

    for (int k = 2; k <= 128; k <<= 1) {
        for (int j = k >> 1; j > 0; j >>= 1) {
            if (tid < 64) {
                const int p = tid;
                const int i = ((p & ~(j - 1)) << 1) | (p & (j - 1));
                const int l = i | j;
                float av = cv[i], bv2 = cv[l];
                int   ai = ci[i], bx = ci[l];
                const bool agtb = (av > bv2) || (av == bv2 && ai < bx);
                const bool desc = ((i & k) == 0);
                if (agtb != desc) { cv[i] = bv2; cv[l] = av; ci[i] = bx; ci[l] = ai; }
            }
            __syncthreads();
        }
    }

    if (tid < 32) {
        const float mx = cv[0];
        float e = __expf(cv[tid] - mx);
        float s2 = e;
        for (int o = 16; o > 0; o >>= 1) s2 += __shfl_xor(s2, o);
        const int fi = ci[tid];
        const int ii = fi >> 5, jj = fi & 31;
        w[(size_t)gid * KNN + tid] = e / s2;
        ind[(size_t)gid * KNN + tid] = si_[ii] * NK + si_[128 + jj];
    }
}

// ----------------------------------- fused PKM gather + residual + LN2 ----
__global__ __launch_bounds__(256) void ln2_pkm_kernel(
    const float* __restrict__ dense, const float* __restrict__ attnf,
    const float* __restrict__ wgt, const int* __restrict__ ind,
    const unsigned short* __restrict__ valb,
    const float* __restrict__ g, const float* __restrict__ bb,
    float* __restrict__ out)
{
    const int t = blockIdx.x, tid = threadIdx.x;
    __shared__ float ws[PH * KNN];
    __shared__ int   is[PH * KNN];
    __shared__ float red[256];
    if (tid < PH * KNN) {
        ws[tid] = wgt[(size_t)t * PH * KNN + tid];
        is[tid] = ind[(size_t)t * PH * KNN + tid];
    }
    __syncthreads();
    float a0 = 0.f, a1 = 0.f, a2 = 0.f;
#pragma unroll 4
    for (int i = 0; i < PH * KNN; i++) {
        const unsigned short* vr = valb + (size_t)is[i] * CD;
        const float wv = ws[i];
        a0 = fmaf(wv, bf2f(vr[tid]), a0);
        a1 = fmaf(wv, bf2f(vr[tid + 256]), a1);
        a2 = fmaf(wv, bf2f(vr[tid + 512]), a2);
    }
    const size_t base = (size_t)t * CD;
    float v0 = a0 + dense[base + tid]       + attnf[base + tid];
    float v1 = a1 + dense[base + tid + 256] + attnf[base + tid + 256];
    float v2 = a2 + dense[base + tid + 512] + attnf[base + tid + 512];

    red[tid] = v0 + v1 + v2; __syncthreads();
    for (int o = 128; o > 0; o >>= 1) { if (tid < o) red[tid] += red[tid + o]; __syncthreads(); }
    const float mean = red[0] * (1.0f / CD); __syncthreads();
    float d0 = v0 - mean, d1 = v1 - mean, d2 = v2 - mean;
    red[tid] = d0 * d0 + d1 * d1 + d2 * d2; __syncthreads();
    for (int o = 128; o > 0; o >>= 1) { if (tid < o) red[tid] += red[tid + o]; __syncthreads(); }
    const float inv = rsqrtf(red[0] * (1.0f / CD) + 1e-12f);
    out[base + tid]       = d0 * inv * g[tid]       + bb[tid];
    out[base + tid + 256] = d1 * inv * g[tid + 256] + bb[tid + 256];
    out[base + tid + 512] = d2 * inv * g[tid + 512] + bb[tid + 512];
}

// ------------------------------------------------------------- launch -----
extern "C" void kernel_launch(void* const* d_in, const int* in_sizes, int n_in,
                              void* d_out, int out_size, void* d_ws, size_t ws_size,
                              hipStream_t stream)
{
    const float* x      = (const float*)d_in[0];
    const float* Wq     = (const float*)d_in[1];
    const float* bq     = (const float*)d_in[2];
    const float* Wk     = (const float*)d_in[3];
    const float* bk     = (const float*)d_in[4];
    const float* Wv     = (const float*)d_in[5];
    const float* bv     = (const float*)d_in[6];
    const float* Wo     = (const float*)d_in[7];
    const float* bo     = (const float*)d_in[8];
    const float* ln1_g  = (const float*)d_in[9];
    const float* ln1_b  = (const float*)d_in[10];
    const float* Wi     = (const float*)d_in[11];
    const float* bi     = (const float*)d_in[12];
    const float* Wd     = (const float*)d_in[13];
    const float* bd     = (const float*)d_in[14];
    const float* ln2_g  = (const float*)d_in[15];
    const float* ln2_b  = (const float*)d_in[16];
    const float* Wpq    = (const float*)d_in[17];
    const float* bpq    = (const float*)d_in[18];
    const float* keys   = (const float*)d_in[19];
    const float* values = (const float*)d_in[20];

    char* W = (char*)d_ws;
    unsigned short* qkvb  = (unsigned short*)(W + 0);
    float*          sbuf  = (float*)(W + 0);
    float*          attnf = (float*)(W + 9437184);
    unsigned short* ctxb  = (unsigned short*)(W + 15728640);
    unsigned short* interb= (unsigned short*)(W + 15728640);
    float*          wgt   = (float*)(W + 15728640);
    int*            ind   = (int*)(W + 16777216);
    unsigned short* xb    = (unsigned short*)(W + 28311552);
    float*          woout = (float*)(W + 28311552);
    float*          dense = (float*)(W + 28311552);
    unsigned short* attnb = (unsigned short*)(W + 34603008);
    unsigned short* pqb   = (unsigned short*)(W + 37748736);
    unsigned short* keysb = (unsigned short*)(W + 46137344);
    unsigned short* wt    = (unsigned short*)(W + 46661632);
    unsigned short* valb  = (unsigned short*)(W + 46661632);  // after last weight GEMM

    const dim3 blk(256);
    const size_t WOFF = 589824;   // 768*768

    // fused prep: weight transposes + x/keys bf16 conversion
    prep_kernel<<<8320, blk, 0, stream>>>(Wq, Wk, Wv, Wo, Wi, Wd, Wpq, wt,
                                          x, xb, keys, keysb);

    // merged QKV projection: [2048][2304] bf16  (TM=64 -> 576 blocks)
    gemm_lds<64, 1, 0, 0, 1><<<dim3(18, 32), blk, 0, stream>>>(
        xb, wt, bq, bk, bv, qkvb, nullptr, CT, 2304, CD, CD, 2304, 0);

    // flash attention (MFMA)
    attn_mfma<<<dim3(8, 12, 4), blk, 0, stream>>>(qkvb, ctxb);

    // output projection + LN1 (TM=32 -> 384 blocks)
    gemm_lds<32, 0, 0, 0, 0><<<dim3(6, 64), blk, 0, stream>>>(
        ctxb, wt + 3 * WOFF, bo, nullptr, nullptr, woout, nullptr, CT, CD, CD, CD, CD, 0);
    ln_kernel<<<CT, blk, 0, stream>>>(attnf, attnb, woout, CD, x, ln1_g, ln1_b);

    // FFN up (GELU, bf16 out)  (TM=64 -> 768 blocks, 3/CU)
    gemm_lds<64, 1, 1, 0, 0><<<dim3(24, 32), blk, 0, stream>>>(
        attnb, wt + 4 * WOFF, bi, nullptr, nullptr, interb, nullptr, CT, CFF, CD, CD, CFF, 0);

    // merged FFN down + PKM query proj (TM=64 -> 704 blocks, 2.75/CU)
    gemm_lds<64, 2, 0, 0, 2><<<dim3(22, 32), blk, 0, stream>>>(
        interb, wt + 4 * WOFF + 2359296, bd, bpq, nullptr, dense, pqb, CT, 2816, CFF, CFF, CD, 2048);

    // values -> bf16 (into dead wt region)
    cvt_bf16x4<<<2048, blk, 0, stream>>>(values, valb, (NK * NK * CD) / 4);

    // PKM scores: 8 batched GEMMs (TM=32 -> 512 blocks, 2/CU)
    gemm_lds<32, 0, 0, 1, 0><<<dim3(1, 64, 8), blk, 0, stream>>>(
        pqb, keysb, nullptr, nullptr, nullptr, sbuf, nullptr, CT, NK, HALF, 2048, PH * 2 * NK, 0);

    // fused two-stage top-k + softmax
    pkm_topk_kernel<<<CT * PH, dim3(128), 0, stream>>>(sbuf, wgt, ind);

    // fused gather + residual + LN2
    ln2_pkm_kernel<<<CT, blk, 0, stream>>>(dense, attnf, wgt, ind, valb,
                                           ln2_g, ln2_b, (float*)d_out);
}